// Round 4
// baseline (282.821 us; speedup 1.0000x reference)
//
#include <hip/hip_runtime.h>

// Problem constants (reference: H = W = 2048, C = 8, N = 1e6)
#define HH 2048
#define WW 2048
#define CC 8
#define MODV 2044.0f     // H - 4
#define NB 128           // row bands: 2044 rows / 16 per band
#define BAND_SHIFT 4     // 16 rows per band -> 16*2048*32B = 1 MB working set

typedef float f32x2 __attribute__((ext_vector_type(2)));
typedef float f32x4 __attribute__((ext_vector_type(4)));

__device__ __forceinline__ f32x4 blerp4(f32x4 tl, f32x4 tr, f32x4 bl, f32x4 br,
                                        float d0, float d1, float m) {
    f32x4 mb = br + d0 * (bl - br);
    f32x4 mt = tr + d0 * (tl - tr);
    return m * (mb + d1 * (mt - mb));
}

// cx, cy are the post-mod coords: cx = (x-1) mod 2044 + 1, in [1, 2045)
__device__ __forceinline__ void mod_coords(f32x2 co, float& cx, float& cy) {
    float x = co.x - 1.0f;
    float y = co.y - 1.0f;
    cx = fmodf(x, MODV); if (cx < 0.0f) cx += MODV; cx += 1.0f;
    cy = fmodf(y, MODV); if (cy < 0.0f) cy += MODV; cy += 1.0f;
}

// Full bilinear interp + store for one point (reference naming preserved:
// tl=V[i0][i1], tr=V[i0+1][i1], bl=V[i0][i1+1], br=V[i0+1][i1+1]).
__device__ __forceinline__ void interp_store(const float* __restrict__ visible,
                                             float* __restrict__ out,
                                             float cx, float cy, unsigned oi) {
    float fx = floorf(cx);
    float fy = floorf(cy);
    float d0 = cx - fx;          // delta along dim 0 (rows)
    float d1 = cy - fy;          // delta along dim 1 (cols)
    int i0 = (int)fx;            // row in [1, 2044]
    int i1 = (int)fy;            // col in [1, 2044]
    float m = (cx > (float)HH) ? 0.0f : 1.0f;   // unreachable, kept for fidelity

    const float* p = visible + ((size_t)i0 * WW + (size_t)i1) * CC;
    const size_t RS = (size_t)WW * CC;
    f32x4 tl0 = *(const f32x4*)(p);
    f32x4 tl1 = *(const f32x4*)(p + 4);
    f32x4 bl0 = *(const f32x4*)(p + 8);        // col+1, contiguous
    f32x4 bl1 = *(const f32x4*)(p + 12);
    f32x4 tr0 = *(const f32x4*)(p + RS);       // row+1
    f32x4 tr1 = *(const f32x4*)(p + RS + 4);
    f32x4 br0 = *(const f32x4*)(p + RS + 8);
    f32x4 br1 = *(const f32x4*)(p + RS + 12);

    f32x4 o0 = blerp4(tl0, tr0, bl0, br0, d0, d1, m);
    f32x4 o1 = blerp4(tl1, tr1, bl1, br1, d0, d1, m);
    float* po = out + (size_t)oi * CC;
    *(f32x4*)po = o0;
    *(f32x4*)(po + 4) = o1;
}

// ---------------- pass 0: zero bin cursors ----------------
__global__ void zero_cnt(unsigned* __restrict__ cnt) {
    cnt[threadIdx.x] = 0u;
}

// ---------------- pass 1: bin points by row-band ----------------
// key layout is XCD-major: key = (band%8)*16 + band/8, so XCD x's 16 bands
// occupy slots [x*16*cap, (x+1)*16*cap) contiguously.
__global__ __launch_bounds__(1024) void bin_points(
    const float* __restrict__ coords,
    const float* __restrict__ visible,   // only for overflow fallback
    float* __restrict__ out,             // only for overflow fallback
    unsigned* __restrict__ cnt,
    float* __restrict__ rcx, float* __restrict__ rcy,
    unsigned* __restrict__ ridx,
    int n, int cap)
{
    __shared__ unsigned lcnt[NB];
    __shared__ unsigned lbase[NB];
    int tid = threadIdx.x;
    if (tid < NB) lcnt[tid] = 0u;
    __syncthreads();

    int i = blockIdx.x * 1024 + tid;
    bool valid = i < n;
    float cx = 1.0f, cy = 1.0f;
    int key = 0;
    unsigned lr = 0;
    if (valid) {
        f32x2 co = reinterpret_cast<const f32x2*>(coords)[i];
        mod_coords(co, cx, cy);
        int i0 = (int)floorf(cx);                 // [1, 2044]
        int band = (i0 - 1) >> BAND_SHIFT;        // [0, 127]
        key = ((band & 7) << 4) | (band >> 3);    // XCD-major
        lr = atomicAdd(&lcnt[key], 1u);           // local rank within block
    }
    __syncthreads();
    if (tid < NB && lcnt[tid]) lbase[tid] = atomicAdd(&cnt[tid], lcnt[tid]);
    __syncthreads();
    if (valid) {
        unsigned p = lbase[key] + lr;
        if (p < (unsigned)cap) {
            int slot = key * cap + (int)p;
            rcx[slot] = cx;
            rcy[slot] = cy;
            ridx[slot] = (unsigned)i;
        } else {
            // bin overflow (statistically never at +8% slack): stay correct,
            // compute this point directly.
            interp_store(visible, out, cx, cy, (unsigned)i);
        }
    }
}

// ---------------- pass 2: gather, XCD-partitioned ----------------
// blockIdx%8 selects the XCD territory (relies on round-robin block->XCD
// dispatch as a locality heuristic only; correctness is placement-free).
// cap is a multiple of 256, so each 256-slot chunk lies in exactly one bin.
__global__ __launch_bounds__(256) void gather_binned(
    const float* __restrict__ visible,
    float* __restrict__ out,
    const unsigned* __restrict__ cnt,
    const float* __restrict__ rcx, const float* __restrict__ rcy,
    const unsigned* __restrict__ ridx,
    int cap)
{
    const int tslots = (NB / 8) * cap;   // 16 bins per XCD territory
    int xcd = blockIdx.x & 7;
    int j   = blockIdx.x >> 3;
    int nbx = gridDim.x >> 3;
    int base = xcd * tslots;

    for (int s0 = j * 256; s0 < tslots; s0 += nbx * 256) {
        int slot = base + s0 + threadIdx.x;
        int bin = slot / cap;            // uniform across the block
        int r = slot - bin * cap;
        unsigned cb = cnt[bin];
        if (cb > (unsigned)cap) cb = (unsigned)cap;
        if ((unsigned)r < cb) {
            float cx = rcx[slot];
            float cy = rcy[slot];
            unsigned oi = ridx[slot];
            interp_store(visible, out, cx, cy, oi);
        }
    }
}

// ---------------- fallback: direct (no workspace) ----------------
__global__ __launch_bounds__(256) void idx2pixel_direct(
    const float* __restrict__ coords,
    const float* __restrict__ visible,
    float* __restrict__ out, int n)
{
    int t = blockIdx.x * blockDim.x + threadIdx.x;
    if (t >= n) return;
    f32x2 co = reinterpret_cast<const f32x2*>(coords)[t];
    float cx, cy;
    mod_coords(co, cx, cy);
    interp_store(visible, out, cx, cy, (unsigned)t);
}

extern "C" void kernel_launch(void* const* d_in, const int* in_sizes, int n_in,
                              void* d_out, int out_size, void* d_ws, size_t ws_size,
                              hipStream_t stream) {
    const float* coords  = (const float*)d_in[0];  // (N, 2) fp32
    const float* visible = (const float*)d_in[1];  // (2048, 2048, 8) fp32
    float* out = (float*)d_out;                    // (N, 8) fp32
    int n = in_sizes[0] / 2;

    // bin capacity: mean + ~8-13% slack, rounded up to 256
    int mean = (n + NB - 1) / NB;
    int margin = mean / 8 + 1024;
    int cap = (mean + margin + 255) & ~255;
    size_t slots = (size_t)NB * (size_t)cap;
    size_t need = 1024 + slots * 12;               // cnt pad + cx,cy,idx SoA

    if (ws_size >= need && n >= (1 << 17)) {
        unsigned* cnt = (unsigned*)d_ws;
        float* rcx = (float*)((char*)d_ws + 1024);
        float* rcy = rcx + slots;
        unsigned* ridx = (unsigned*)(rcy + slots);

        zero_cnt<<<1, NB, 0, stream>>>(cnt);
        int nb1 = (n + 1023) / 1024;
        bin_points<<<nb1, 1024, 0, stream>>>(coords, visible, out, cnt,
                                             rcx, rcy, ridx, n, cap);
        gather_binned<<<2048, 256, 0, stream>>>(visible, out, cnt,
                                                rcx, rcy, ridx, cap);
    } else {
        int block = 256;
        int grid = (n + block - 1) / block;
        idx2pixel_direct<<<grid, block, 0, stream>>>(coords, visible, out, n);
    }
}